// Round 8
// baseline (7341.252 us; speedup 1.0000x reference)
//
#include <hip/hip_runtime.h>
#include <math.h>

// QuantumMambaSSMCore R14 = R13 body + WORKING register-budget pin.
// R12/R13 showed hipcc ignores __launch_bounds__'s 2nd arg: VGPR stayed 64 and
// ~50 regs spilled (FETCH/WRITE 10x, VALUBusy 10%). R14 pins the budget with
// amdgpu_waves_per_eu(4,4) + amdgpu_flat_work_group_size(1024,1024):
// 4 waves/EU = the one resident dual-element block -> 128-VGPR cap; the
// R9-proven body needs ~112.
// 64 blocks x 1024 thr (16 waves); waves 0-7 = element 2b, waves 8-15 = 2b+1.
//  - Tables packed to 120B/record; exchange buffers use R11's k-layout +
//    GF(2)-verified swizzle (bank conflicts measured 6.2e4 = floor).
//  - Phase B: register-cheap PW sign-mask loop (R9 form).

#define PIF 3.14159265358979323846f

constexpr int NQ = 10, SEQ = 512, NBATCH = 128, NTHR = 1024, NBLK = 64;

// ---- QSVT phase masks (frame-0), verified R7-R13 ----
struct CTbl { int mz[4][NQ]; };
constexpr CTbl build_tbl() {
  CTbl t{};
  unsigned mrow[NQ];
  for (int b = 0; b < NQ; ++b) mrow[b] = 1u << b;
  for (int d = 0; d < 4; ++d) {
    for (int i = 0; i < NQ; ++i) t.mz[d][i] = (int)mrow[9 - i];
    for (int i = 0; i < NQ - 1; ++i) { int bc = 9 - i, bt = 8 - i; mrow[bt] ^= mrow[bc]; }
    mrow[9] ^= mrow[0];
  }
  return t;
}
constexpr CTbl CT = build_tbl();

// ---- permutation columns (circuit order), verified R8-R13 ----
struct PermCols { int c4[10]; int cL[10]; };
constexpr PermCols build_perms() {
  PermCols P{};
  for (int b = 0; b < 10; ++b) {
    int x = 1 << b;
    for (int d = 0; d < 4; ++d) {
      for (int i = 0; i < 9; ++i) { int bc = 9 - i, bt = 8 - i; if ((x >> bc) & 1) x ^= (1 << bt); }
      if (x & 1) x ^= (1 << 9);
    }
    P.c4[b] = x;
    int y = 1 << b;
    for (int i = 0; i < 9; ++i) { int bc = 9 - i, bt = 8 - i; if ((y >> bc) & 1) y ^= (1 << bt); }
    P.cL[b] = y;
  }
  return P;
}
constexpr PermCols PC = build_perms();

constexpr int lanePart(int x)  { return ((x >> 0) & 1) | (((x >> 5) & 1) << 1) |
                                        (((x >> 1) & 1) << 2) | (((x >> 7) & 1) << 3) |
                                        (((x >> 3) & 1) << 4) | (((x >> 9) & 1) << 5); }
constexpr int wavePart8(int x) { return ((x >> 4) & 1) | (((x >> 8) & 1) << 1) |
                                        (((x >> 6) & 1) << 2); }

// x-index -> storage index k (reg bit x2 = k0 so reg-pairs are adjacent)
constexpr int kmap(int x) {
  return ((x >> 2) & 1)
       | (((x >> 0) & 1) << 1) | (((x >> 5) & 1) << 2) | (((x >> 1) & 1) << 3)
       | (((x >> 7) & 1) << 4) | (((x >> 3) & 1) << 5) | (((x >> 9) & 1) << 6)
       | (((x >> 4) & 1) << 7) | (((x >> 8) & 1) << 8) | (((x >> 6) & 1) << 9);
}
constexpr int swzk(int k) { return k ^ (((k >> 5) & 1) << 1) ^ (((k >> 4) & 1) << 2); }

constexpr int SKC4 = swzk(kmap(PC.c4[2]));
constexpr int SKCL = swzk(kmap(PC.cL[2]));

typedef __attribute__((ext_vector_type(2))) float v2;

// ---------------- cross-lane exchange helpers ----------------
template<int C>
__device__ __forceinline__ int dpp1(int x) {
  return __builtin_amdgcn_update_dpp(x, x, C, 0xF, 0xF, false);
}
template<int VL>
__device__ __forceinline__ int lxi(int x) {
  if constexpr (VL == 1)  return dpp1<0xB1>(x);
  else if constexpr (VL == 2)  return dpp1<0x4E>(x);
  else if constexpr (VL == 3)  return dpp1<0x1B>(x);
  else if constexpr (VL <= 7) {
    constexpr int q = (VL & 3) ^ 3;
    int y = x;
    if constexpr (q == 1) y = dpp1<0xB1>(y);
    else if constexpr (q == 2) y = dpp1<0x4E>(y);
    else if constexpr (q == 3) y = dpp1<0x1B>(y);
    return dpp1<0x141>(y);
  } else if constexpr (VL >= 12) {
    constexpr int q = (VL & 3) ^ 3;
    int y = x;
    if constexpr (q == 1) y = dpp1<0xB1>(y);
    else if constexpr (q == 2) y = dpp1<0x4E>(y);
    else if constexpr (q == 3) y = dpp1<0x1B>(y);
    return dpp1<0x140>(y);
  } else {
    constexpr int a = VL & 3;
    int y = x;
    if constexpr (a == 1) y = dpp1<0xB1>(y);
    else if constexpr (a == 2) y = dpp1<0x4E>(y);
    else if constexpr (a == 3) y = dpp1<0x1B>(y);
    y = dpp1<0x141>(y);
    return dpp1<0x140>(y);
  }
}
template<int VL>
__device__ __forceinline__ float lx(float x) {
  if constexpr (VL == 0) return x;
  else if constexpr (VL & 32) {
    int addr = (((int)threadIdx.x & 63) ^ VL) << 2;
    return __int_as_float(__builtin_amdgcn_ds_bpermute(addr, __float_as_int(x)));
  } else if constexpr (VL & 16) {
    return __int_as_float(__builtin_amdgcn_ds_swizzle(__float_as_int(x), (VL << 10) | 0x1F));
  } else {
    return __int_as_float(lxi<VL>(__float_as_int(x)));
  }
}
__device__ __forceinline__ float rdl(float x, int l) {
  return __int_as_float(__builtin_amdgcn_readlane(__float_as_int(x), l));
}

// ---------------- SU(2) application over 2 regs (R9, inline selects) ----------------
__device__ __forceinline__ void apply2(v2* amp, const v2* p, bool par, float4 U0, float4 U1) {
  v2 u00 = {U0.x, U0.y}, u01 = {U0.z, U0.w}, u10 = {U1.x, U1.y}, u11 = {U1.z, U1.w};
  v2 A = par ? u11 : u00, B = par ? u10 : u01;
  v2 An = {-A.y, A.y}, Bn = {-B.y, B.y};
#pragma unroll
  for (int r = 0; r < 2; ++r) {
    v2 o = amp[r], q = p[r];
    v2 res = A.x * o;
    res += An * __builtin_shufflevector(o, o, 1, 0);
    res += B.x * q;
    res += Bn * __builtin_shufflevector(q, q, 1, 0);
    amp[r] = res;
  }
}

template<int VL>
__device__ __forceinline__ void gate_lane2(v2* amp, float4 U0, float4 U1, int lane) {
  v2 p[2];
#pragma unroll
  for (int r = 0; r < 2; ++r) { p[r].x = lx<VL>(amp[r].x); p[r].y = lx<VL>(amp[r].y); }
  apply2(amp, p, (lane & VL) != 0, U0, U1);
}

__device__ __forceinline__ void gate_reg1(v2* amp, float4 U0, float4 U1) {
  v2 u00 = {U0.x, U0.y}, u01 = {U0.z, U0.w}, u10 = {U1.x, U1.y}, u11 = {U1.z, U1.w};
  v2 o0 = amp[0], o1 = amp[1];
  v2 a0, a1;
  a0.x = u00.x * o0.x - u00.y * o0.y + u01.x * o1.x - u01.y * o1.y;
  a0.y = u00.x * o0.y + u00.y * o0.x + u01.x * o1.y + u01.y * o1.x;
  a1.x = u10.x * o0.x - u10.y * o0.y + u11.x * o1.x - u11.y * o1.y;
  a1.y = u10.x * o0.y + u10.y * o0.x + u11.x * o1.y + u11.y * o1.x;
  amp[0] = a0; amp[1] = a1;
}

template<int VL>
__device__ __forceinline__ float xdot_lane2(const v2* amp) {
  v2 acc = {0.f, 0.f};
#pragma unroll
  for (int r = 0; r < 2; ++r) {
    v2 p; p.x = lx<VL>(amp[r].x); p.y = lx<VL>(amp[r].y);
    acc += amp[r] * p;
  }
  return acc.x + acc.y;
}

// ---------------- main kernel: 2 batch elements per block ----------------
__global__ void
__attribute__((amdgpu_flat_work_group_size(1024, 1024), amdgpu_waves_per_eu(4, 4)))
qmamba_main(
    const float* __restrict__ angles, const float* __restrict__ Wx,
    const float* __restrict__ Wdt, const float* __restrict__ bdt,
    const float* __restrict__ pc, const float* __restrict__ cp,
    float* __restrict__ out)
{
  __shared__ __align__(16) float tbl[2][SEQ][30];      // 122880 B (packed records)
  __shared__ float4 uuL[40];                           // 640 B
  __shared__ __align__(16) v2 ex[2][2][1024];          // 32768 B
  __shared__ float  zb[2][8][16];                      // 1024 B

  const int tid  = threadIdx.x;
  const int lane = tid & 63;
  const int wave = tid >> 6;
  const int el   = wave >> 3;       // element within block
  const int wv   = wave & 7;        // wave within element
  const int bel  = blockIdx.x * 2 + el;

  // prologue 1: fused variational unitaries U = RZ(g)*RY(be)*RX(al)
  if (tid < 20) {
    int k = tid * 3;
    float al = 0.5f * cp[k], be = 0.5f * cp[k + 1], ga = 0.5f * cp[k + 2];
    float ca = __cosf(al), sa = __sinf(al);
    float cb = __cosf(be), sb = __sinf(be);
    float cg = __cosf(ga), sg = __sinf(ga);
    float2 M00 = make_float2(cb * ca,  sb * sa);
    float2 M01 = make_float2(-sb * ca, -cb * sa);
    float2 M10 = make_float2(sb * ca,  -cb * sa);
    float2 M11 = make_float2(cb * ca,  -sb * sa);
    float2 e0 = make_float2(cg, -sg), e1 = make_float2(cg, sg);
    auto cm = [](float2 a, float2 c) {
      return make_float2(a.x * c.x - a.y * c.y, a.x * c.y + a.y * c.x);
    };
    float2 u00 = cm(M00, e0), u01 = cm(M01, e0), u10 = cm(M10, e1), u11 = cm(M11, e1);
    uuL[2 * tid]     = make_float4(u00.x, u00.y, u01.x, u01.y);
    uuL[2 * tid + 1] = make_float4(u10.x, u10.y, u11.x, u11.y);
  }

  // prologue 2: per-step tables (el = tid>>9, t = tid&511)
  {
    const int pel = tid >> 9, t = tid & (SEQ - 1);
    const int pb  = blockIdx.x * 2 + pel;
    const float* ar = angles + (size_t)(pb * SEQ + t) * NQ;
    float a[NQ];
#pragma unroll
    for (int n = 0; n < NQ; ++n) a[n] = ar[n];
    float dtr[5];
#pragma unroll
    for (int r = 0; r < 5; ++r) {
      float acc = 0.f;
#pragma unroll
      for (int n = 0; n < NQ; ++n) acc += a[n] * Wx[r * NQ + n];
      dtr[r] = acc;
    }
    float* rec = &tbl[pel][t][0];
#pragma unroll
    for (int w = 0; w < NQ; ++w) {
      float lin = bdt[w];
#pragma unroll
      for (int r = 0; r < 5; ++r) lin += dtr[r] * Wdt[w * 5 + r];
      float sp = lin > 0.f ? lin + log1pf(__expf(-lin)) : log1pf(__expf(lin));
      float th = tanhf(sp) * PIF;
      float fa = a[w] * th;
      rec[w]      = th;
      rec[10 + w] = __cosf(fa);
      rec[20 + w] = __sinf(fa);
    }
  }
  __syncthreads();

  float pch[4];
#pragma unroll
  for (int d = 0; d < 4; ++d) pch[d] = 0.5f * pc[d] * PIF;

  // wave-gate flat-sum coefficients (wires 5,1,3 <-> v bits 0,1,2)
  v2 cw0[8], cw1[8];
  {
    const int s5 = wv & 1, s1 = (wv >> 1) & 1, s3 = (wv >> 2) & 1;
    auto ent = [&](int g, int row, int col) -> v2 {
      float4 R = uuL[2 * g + row];
      return col ? v2{R.z, R.w} : v2{R.x, R.y};
    };
    auto cmul = [](v2 a, v2 c) -> v2 {
      return v2{a.x * c.x - a.y * c.y, a.x * c.y + a.y * c.x};
    };
#pragma unroll
    for (int v = 0; v < 8; ++v) {
      const int v5 = v & 1, v1 = (v >> 1) & 1, v3 = (v >> 2) & 1;
      cw0[v] = cmul(cmul(ent(5,  s5, s5 ^ v5), ent(1,  s1, s1 ^ v1)), ent(3,  s3, s3 ^ v3));
      cw1[v] = cmul(cmul(ent(15, s5, s5 ^ v5), ent(11, s1, s1 ^ v1)), ent(13, s3, s3 ^ v3));
    }
  }

  // Phase-B sign bits (register-cheap R9 form)
  unsigned PW0 = 0, PW1 = 0;
#pragma unroll
  for (int k = 0; k < 40; ++k) {
    const int m  = CT.mz[k / 10][k % 10];
    const int lm = lanePart(m), wm = wavePart8(m);
    unsigned flip = ((unsigned)((__popc(lane & lm) ^ __popc(wv & wm)) & 1)) ^ 1u;
    if (k < 32) PW0 |= flip << k; else PW1 |= flip << (k - 32);
  }

  // permutation write bases in storage space (R11-verified)
  int d4k = 0, dLk = 0;
  if (lane & 1)  { d4k ^= kmap(PC.c4[0]); dLk ^= kmap(PC.cL[0]); }
  if (lane & 2)  { d4k ^= kmap(PC.c4[5]); dLk ^= kmap(PC.cL[5]); }
  if (lane & 4)  { d4k ^= kmap(PC.c4[1]); dLk ^= kmap(PC.cL[1]); }
  if (lane & 8)  { d4k ^= kmap(PC.c4[7]); dLk ^= kmap(PC.cL[7]); }
  if (lane & 16) { d4k ^= kmap(PC.c4[3]); dLk ^= kmap(PC.cL[3]); }
  if (lane & 32) { d4k ^= kmap(PC.c4[9]); dLk ^= kmap(PC.cL[9]); }
  if (wv & 1)    { d4k ^= kmap(PC.c4[4]); dLk ^= kmap(PC.cL[4]); }
  if (wv & 2)    { d4k ^= kmap(PC.c4[8]); dLk ^= kmap(PC.cL[8]); }
  if (wv & 4)    { d4k ^= kmap(PC.c4[6]); dLk ^= kmap(PC.cL[6]); }
  const int sd4  = swzk(d4k);
  const int sdL  = swzk(dLk);
  const int sown = swzk((lane << 1) | (wv << 7));   // own r=0 storage slot (even)

  v2* const exA = &ex[el][0][0];
  v2* const exB = &ex[el][1][0];

  float hcw[NQ], hsw[NQ];
#pragma unroll
  for (int w = 0; w < NQ; ++w) { hcw[w] = 1.f; hsw[w] = 0.f; }

  v2 amp[2];

#pragma unroll 1
  for (int t = 0; t < SEQ; ++t) {
    float thv[10];
    {
      const float2* rq = (const float2*)&tbl[el][t][0];
#pragma unroll
      for (int j = 0; j < 5; ++j) { float2 q = rq[j]; thv[2 * j] = q.x; thv[2 * j + 1] = q.y; }
    }

    // ---- Phase A: real product state from RY(h)|0>
    float F;
    F  = (lane & 1)  ? hsw[9] : hcw[9];
    F *= (lane & 2)  ? hsw[4] : hcw[4];
    F *= (lane & 4)  ? hsw[8] : hcw[8];
    F *= (lane & 8)  ? hsw[2] : hcw[2];
    F *= (lane & 16) ? hsw[6] : hcw[6];
    F *= (lane & 32) ? hsw[0] : hcw[0];
    F *= (wv & 1)    ? hsw[5] : hcw[5];
    F *= (wv & 2)    ? hsw[1] : hcw[1];
    F *= (wv & 4)    ? hsw[3] : hcw[3];
    const float G0 = F * hcw[7];
    const float G1 = F * hsw[7];

    // ---- Phase B: fused 40-RZ phase
    float S0 = 0.f, S1 = 0.f;
#pragma unroll
    for (int k = 0; k < 40; ++k) {
      const int m  = CT.mz[k / 10][k % 10];
      float v = pch[k / 10] * thv[k % 10];
      unsigned fl = ((k < 32 ? (PW0 >> k) : (PW1 >> (k - 32))) & 1u) << 31;
      float sv = __int_as_float(__float_as_int(v) ^ fl);
      if ((m >> 2) & 1) S1 += sv; else S0 += sv;
    }
    {
      float sn, cs;
      __sincosf(S0 + S1, &sn, &cs); amp[0].x = G0 * cs; amp[0].y = G0 * sn;
      __sincosf(S0 - S1, &sn, &cs); amp[1].x = G1 * cs; amp[1].y = G1 * sn;
    }

    // ---- P4 permute merged with layer-0 wave gates ----
    exA[sd4]        = amp[0];
    exA[sd4 ^ SKC4] = amp[1];
    __syncthreads();
    {
      const float4* q4 = (const float4*)exA;
      v2 a0 = {0.f, 0.f}, a1 = {0.f, 0.f};
#pragma unroll
      for (int v = 0; v < 8; ++v) {
        float4 q = q4[(sown ^ (v << 7)) >> 1];     // (r0.x r0.y r1.x r1.y)
        v2 c = cw0[v];
        a0.x += c.x * q.x - c.y * q.y;  a0.y += c.x * q.y + c.y * q.x;
        a1.x += c.x * q.z - c.y * q.w;  a1.y += c.x * q.w + c.y * q.z;
      }
      amp[0] = a0; amp[1] = a1;
    }
    // layer-0 local gates
    gate_lane2<32>(amp, uuL[0],  uuL[1],  lane);
    gate_lane2<8> (amp, uuL[4],  uuL[5],  lane);
    gate_lane2<2> (amp, uuL[8],  uuL[9],  lane);
    gate_lane2<16>(amp, uuL[12], uuL[13], lane);
    gate_reg1     (amp, uuL[14], uuL[15]);
    gate_lane2<4> (amp, uuL[16], uuL[17], lane);
    gate_lane2<1> (amp, uuL[18], uuL[19], lane);

    // ---- PL permute merged with layer-1 wave gates ----
    exB[sdL]        = amp[0];
    exB[sdL ^ SKCL] = amp[1];
    __syncthreads();
    {
      const float4* q4 = (const float4*)exB;
      v2 a0 = {0.f, 0.f}, a1 = {0.f, 0.f};
#pragma unroll
      for (int v = 0; v < 8; ++v) {
        float4 q = q4[(sown ^ (v << 7)) >> 1];
        v2 c = cw1[v];
        a0.x += c.x * q.x - c.y * q.y;  a0.y += c.x * q.y + c.y * q.x;
        a1.x += c.x * q.z - c.y * q.w;  a1.y += c.x * q.w + c.y * q.z;
      }
      amp[0] = a0; amp[1] = a1;
    }
    // layer-1 local gates
    gate_lane2<32>(amp, uuL[20], uuL[21], lane);
    gate_lane2<8> (amp, uuL[24], uuL[25], lane);
    gate_lane2<2> (amp, uuL[28], uuL[29], lane);
    gate_lane2<16>(amp, uuL[32], uuL[33], lane);
    gate_reg1     (amp, uuL[34], uuL[35]);
    gate_lane2<4> (amp, uuL[36], uuL[37], lane);
    gate_lane2<1> (amp, uuL[38], uuL[39], lane);

    // ---- final PL permute merged with measurement ----
    exA[sdL]        = amp[0];
    exA[sdL ^ SKCL] = amp[1];
    __syncthreads();
    v2 pw5[2], pw1[2], pw3[2];
    {
      const float4* q4 = (const float4*)exA;
      float4 qs = q4[sown >> 1];
      float4 q5 = q4[(sown ^ (1 << 7)) >> 1];
      float4 q1 = q4[(sown ^ (2 << 7)) >> 1];
      float4 q3 = q4[(sown ^ (4 << 7)) >> 1];
      amp[0] = v2{qs.x, qs.y}; amp[1] = v2{qs.z, qs.w};
      pw5[0] = v2{q5.x, q5.y}; pw5[1] = v2{q5.z, q5.w};
      pw1[0] = v2{q1.x, q1.y}; pw1[1] = v2{q1.z, q1.w};
      pw3[0] = v2{q3.x, q3.y}; pw3[1] = v2{q3.z, q3.w};
    }

    float cfv[10], sfv[10];
    {
      const float2* rq = (const float2*)&tbl[el][t][0];
#pragma unroll
      for (int j = 0; j < 5; ++j) {
        float2 qc = rq[5 + j], qsn = rq[10 + j];
        cfv[2 * j] = qc.x; cfv[2 * j + 1] = qc.y;
        sfv[2 * j] = qsn.x; sfv[2 * j + 1] = qsn.y;
      }
    }

    const float n0 = amp[0].x * amp[0].x + amp[0].y * amp[0].y;
    const float n1 = amp[1].x * amp[1].x + amp[1].y * amp[1].y;
    const float T0 = n0 + n1;
    const float T1 = n0 - n1;

    auto vdot2 = [](const v2* a, const v2* p) {
      v2 acc = a[0] * p[0] + a[1] * p[1];
      return acc.x + acc.y;
    };

    float zv[NQ];
    { float zp = (lane & 32) ? -T0 : T0; zv[0] = cfv[0] * zp - sfv[0] * xdot_lane2<32>(amp); }
    { float zp = (wv & 2)    ? -T0 : T0; zv[1] = cfv[1] * zp - sfv[1] * vdot2(amp, pw1); }
    { float zp = (lane & 8)  ? -T0 : T0; zv[2] = cfv[2] * zp - sfv[2] * xdot_lane2<8>(amp); }
    { float zp = (wv & 4)    ? -T0 : T0; zv[3] = cfv[3] * zp - sfv[3] * vdot2(amp, pw3); }
    { float zp = (lane & 2)  ? -T0 : T0; zv[4] = cfv[4] * zp - sfv[4] * xdot_lane2<2>(amp); }
    { float zp = (wv & 1)    ? -T0 : T0; zv[5] = cfv[5] * zp - sfv[5] * vdot2(amp, pw5); }
    { float zp = (lane & 16) ? -T0 : T0; zv[6] = cfv[6] * zp - sfv[6] * xdot_lane2<16>(amp); }
    { float xr = 2.f * (amp[0].x * amp[1].x + amp[0].y * amp[1].y);
      zv[7] = cfv[7] * T1 - sfv[7] * xr; }
    { float zp = (lane & 4)  ? -T0 : T0; zv[8] = cfv[8] * zp - sfv[8] * xdot_lane2<4>(amp); }
    { float zp = (lane & 1)  ? -T0 : T0; zv[9] = cfv[9] * zp - sfv[9] * xdot_lane2<1>(amp); }

    // per-wave lane reduction: 3 DPP stages + pack + 3 stages
#pragma unroll
    for (int w = 0; w < NQ; ++w) {
      zv[w] += lx<1>(zv[w]);
      zv[w] += lx<2>(zv[w]);
      zv[w] += lx<4>(zv[w]);
    }
    const int l7 = lane & 7;
    float c01 = (l7 & 1) ? zv[1] : zv[0];
    float c23 = (l7 & 1) ? zv[3] : zv[2];
    float c45 = (l7 & 1) ? zv[5] : zv[4];
    float c67 = (l7 & 1) ? zv[7] : zv[6];
    float c03 = (l7 & 2) ? c23 : c01;
    float c47 = (l7 & 2) ? c67 : c45;
    float pk  = (l7 & 4) ? c47 : c03;
    pk += lx<8>(pk);  pk += lx<16>(pk);  pk += lx<32>(pk);
    float z8 = zv[8]; z8 += lx<8>(z8); z8 += lx<16>(z8); z8 += lx<32>(z8);
    float z9 = zv[9]; z9 += lx<8>(z9); z9 += lx<16>(z9); z9 += lx<32>(z9);
    float zsel = pk;
    zsel = (lane == 8) ? z8 : zsel;
    zsel = (lane == 9) ? z9 : zsel;

    // cross-wave combine (per element) + raw z store + h for next step
    if (lane < NQ) zb[el][wv][lane] = zsel;
    __syncthreads();
    float z = 0.f;
    if (lane < NQ) {
      z = zb[el][0][lane] + zb[el][1][lane] + zb[el][2][lane] + zb[el][3][lane]
        + zb[el][4][lane] + zb[el][5][lane] + zb[el][6][lane] + zb[el][7][lane];
      if (wv == 0) out[(size_t)(bel * SEQ + t) * NQ + lane] = z;
    }
    float sn_h, cs_h;
    __sincosf(0.5f * z, &sn_h, &cs_h);
#pragma unroll
    for (int w = 0; w < NQ; ++w) { hcw[w] = rdl(cs_h, w); hsw[w] = rdl(sn_h, w); }
  }
}

// ---------------- post kernel: out = C*z + D*a, in place ----------------
__global__ __launch_bounds__(256) void qmamba_post(
    const float* __restrict__ angles, const float* __restrict__ Wx,
    const float* __restrict__ Dg, float* __restrict__ out)
{
  int i = blockIdx.x * 256 + threadIdx.x;
  if (i >= NBATCH * SEQ * NQ) return;
  int w  = i % NQ;
  int bt = i / NQ;
  const float* a = angles + (size_t)bt * NQ;
  float C = 0.f;
#pragma unroll
  for (int n = 0; n < NQ; ++n) C += a[n] * Wx[(15 + w) * NQ + n];
  float z = out[i];
  out[i] = C * z + Dg[w] * a[w];
}

extern "C" void kernel_launch(void* const* d_in, const int* in_sizes, int n_in,
                              void* d_out, int out_size, void* d_ws, size_t ws_size,
                              hipStream_t stream) {
  (void)in_sizes; (void)n_in; (void)out_size; (void)d_ws; (void)ws_size;
  const float* angles = (const float*)d_in[0];
  const float* Wx     = (const float*)d_in[1];
  const float* Wdt    = (const float*)d_in[2];
  const float* bdt    = (const float*)d_in[3];
  const float* pc     = (const float*)d_in[4];
  const float* cp     = (const float*)d_in[5];
  const float* Dg     = (const float*)d_in[6];
  float* out = (float*)d_out;
  hipLaunchKernelGGL(qmamba_main, dim3(NBLK), dim3(NTHR), 0, stream,
                     angles, Wx, Wdt, bdt, pc, cp, out);
  hipLaunchKernelGGL(qmamba_post, dim3((NBATCH * SEQ * NQ + 255) / 256), dim3(256), 0, stream,
                     angles, Wx, Dg, out);
}

// Round 9
// 2098.188 us; speedup vs baseline: 3.4989x; 3.4989x over previous
//
#include <hip/hip_runtime.h>
#include <math.h>

// QuantumMambaSSMCore R15: R9 shape (512 thr, 1 element/block, 128 blocks,
// launch_bounds(512,2) -> proven 112-VGPR no-spill regime) + the R12-R14
// CORRECTNESS-VERIFIED body improvements:
//  - k-layout exchange storage (reg bit = storage LSB): merge reads are
//    aligned ds_read_b128 (8/merge vs 16 b64), final-perm reads 4 b128 vs 10.
//  - GF(2)-verified swizzle swzk: bank conflicts at the 6.2e4 floor
//    (R9 measured 5.05e7 ~= 7% of step time).
//  - Packed 30-float tables (th10|cf10|sf10).
// R12-R14's only failure was hipcc pinning 1024-thr blocks at 64 VGPR (spills);
// at 512 thr the allocator gives ~112 (R9-proven).

#define PIF 3.14159265358979323846f

constexpr int NQ = 10, SEQ = 512, NB = 128, NTHR = 512;

// ---- QSVT phase masks (frame-0), verified R7-R14 ----
struct CTbl { int mz[4][NQ]; };
constexpr CTbl build_tbl() {
  CTbl t{};
  unsigned mrow[NQ];
  for (int b = 0; b < NQ; ++b) mrow[b] = 1u << b;
  for (int d = 0; d < 4; ++d) {
    for (int i = 0; i < NQ; ++i) t.mz[d][i] = (int)mrow[9 - i];
    for (int i = 0; i < NQ - 1; ++i) { int bc = 9 - i, bt = 8 - i; mrow[bt] ^= mrow[bc]; }
    mrow[9] ^= mrow[0];
  }
  return t;
}
constexpr CTbl CT = build_tbl();

// ---- permutation columns (circuit order), verified R8-R14 ----
struct PermCols { int c4[10]; int cL[10]; };
constexpr PermCols build_perms() {
  PermCols P{};
  for (int b = 0; b < 10; ++b) {
    int x = 1 << b;
    for (int d = 0; d < 4; ++d) {
      for (int i = 0; i < 9; ++i) { int bc = 9 - i, bt = 8 - i; if ((x >> bc) & 1) x ^= (1 << bt); }
      if (x & 1) x ^= (1 << 9);
    }
    P.c4[b] = x;
    int y = 1 << b;
    for (int i = 0; i < 9; ++i) { int bc = 9 - i, bt = 8 - i; if ((y >> bc) & 1) y ^= (1 << bt); }
    P.cL[b] = y;
  }
  return P;
}
constexpr PermCols PC = build_perms();

constexpr int lanePart(int x)  { return ((x >> 0) & 1) | (((x >> 5) & 1) << 1) |
                                        (((x >> 1) & 1) << 2) | (((x >> 7) & 1) << 3) |
                                        (((x >> 3) & 1) << 4) | (((x >> 9) & 1) << 5); }
constexpr int wavePart8(int x) { return ((x >> 4) & 1) | (((x >> 8) & 1) << 1) |
                                        (((x >> 6) & 1) << 2); }

// x-index -> storage index k (reg bit x2 = k0 so reg-pairs are adjacent)
constexpr int kmap(int x) {
  return ((x >> 2) & 1)
       | (((x >> 0) & 1) << 1) | (((x >> 5) & 1) << 2) | (((x >> 1) & 1) << 3)
       | (((x >> 7) & 1) << 4) | (((x >> 3) & 1) << 5) | (((x >> 9) & 1) << 6)
       | (((x >> 4) & 1) << 7) | (((x >> 8) & 1) << 8) | (((x >> 6) & 1) << 9);
}
constexpr int swzk(int k) { return k ^ (((k >> 5) & 1) << 1) ^ (((k >> 4) & 1) << 2); }

constexpr int SKC4 = swzk(kmap(PC.c4[2]));
constexpr int SKCL = swzk(kmap(PC.cL[2]));

typedef __attribute__((ext_vector_type(2))) float v2;

// ---------------- cross-lane exchange helpers ----------------
template<int C>
__device__ __forceinline__ int dpp1(int x) {
  return __builtin_amdgcn_update_dpp(x, x, C, 0xF, 0xF, false);
}
template<int VL>
__device__ __forceinline__ int lxi(int x) {
  if constexpr (VL == 1)  return dpp1<0xB1>(x);
  else if constexpr (VL == 2)  return dpp1<0x4E>(x);
  else if constexpr (VL == 3)  return dpp1<0x1B>(x);
  else if constexpr (VL <= 7) {
    constexpr int q = (VL & 3) ^ 3;
    int y = x;
    if constexpr (q == 1) y = dpp1<0xB1>(y);
    else if constexpr (q == 2) y = dpp1<0x4E>(y);
    else if constexpr (q == 3) y = dpp1<0x1B>(y);
    return dpp1<0x141>(y);
  } else if constexpr (VL >= 12) {
    constexpr int q = (VL & 3) ^ 3;
    int y = x;
    if constexpr (q == 1) y = dpp1<0xB1>(y);
    else if constexpr (q == 2) y = dpp1<0x4E>(y);
    else if constexpr (q == 3) y = dpp1<0x1B>(y);
    return dpp1<0x140>(y);
  } else {
    constexpr int a = VL & 3;
    int y = x;
    if constexpr (a == 1) y = dpp1<0xB1>(y);
    else if constexpr (a == 2) y = dpp1<0x4E>(y);
    else if constexpr (a == 3) y = dpp1<0x1B>(y);
    y = dpp1<0x141>(y);
    return dpp1<0x140>(y);
  }
}
template<int VL>
__device__ __forceinline__ float lx(float x) {
  if constexpr (VL == 0) return x;
  else if constexpr (VL & 32) {
    int addr = (((int)threadIdx.x & 63) ^ VL) << 2;
    return __int_as_float(__builtin_amdgcn_ds_bpermute(addr, __float_as_int(x)));
  } else if constexpr (VL & 16) {
    return __int_as_float(__builtin_amdgcn_ds_swizzle(__float_as_int(x), (VL << 10) | 0x1F));
  } else {
    return __int_as_float(lxi<VL>(__float_as_int(x)));
  }
}
__device__ __forceinline__ float rdl(float x, int l) {
  return __int_as_float(__builtin_amdgcn_readlane(__float_as_int(x), l));
}

// ---------------- SU(2) application over 2 regs (R9, inline selects) ----------------
__device__ __forceinline__ void apply2(v2* amp, const v2* p, bool par, float4 U0, float4 U1) {
  v2 u00 = {U0.x, U0.y}, u01 = {U0.z, U0.w}, u10 = {U1.x, U1.y}, u11 = {U1.z, U1.w};
  v2 A = par ? u11 : u00, B = par ? u10 : u01;
  v2 An = {-A.y, A.y}, Bn = {-B.y, B.y};
#pragma unroll
  for (int r = 0; r < 2; ++r) {
    v2 o = amp[r], q = p[r];
    v2 res = A.x * o;
    res += An * __builtin_shufflevector(o, o, 1, 0);
    res += B.x * q;
    res += Bn * __builtin_shufflevector(q, q, 1, 0);
    amp[r] = res;
  }
}

template<int VL>
__device__ __forceinline__ void gate_lane2(v2* amp, float4 U0, float4 U1, int lane) {
  v2 p[2];
#pragma unroll
  for (int r = 0; r < 2; ++r) { p[r].x = lx<VL>(amp[r].x); p[r].y = lx<VL>(amp[r].y); }
  apply2(amp, p, (lane & VL) != 0, U0, U1);
}

__device__ __forceinline__ void gate_reg1(v2* amp, float4 U0, float4 U1) {
  v2 u00 = {U0.x, U0.y}, u01 = {U0.z, U0.w}, u10 = {U1.x, U1.y}, u11 = {U1.z, U1.w};
  v2 o0 = amp[0], o1 = amp[1];
  v2 a0, a1;
  a0.x = u00.x * o0.x - u00.y * o0.y + u01.x * o1.x - u01.y * o1.y;
  a0.y = u00.x * o0.y + u00.y * o0.x + u01.x * o1.y + u01.y * o1.x;
  a1.x = u10.x * o0.x - u10.y * o0.y + u11.x * o1.x - u11.y * o1.y;
  a1.y = u10.x * o0.y + u10.y * o0.x + u11.x * o1.y + u11.y * o1.x;
  amp[0] = a0; amp[1] = a1;
}

template<int VL>
__device__ __forceinline__ float xdot_lane2(const v2* amp) {
  v2 acc = {0.f, 0.f};
#pragma unroll
  for (int r = 0; r < 2; ++r) {
    v2 p; p.x = lx<VL>(amp[r].x); p.y = lx<VL>(amp[r].y);
    acc += amp[r] * p;
  }
  return acc.x + acc.y;
}

// ---------------- main kernel: one element per block, 8 waves ----------------
__global__ __launch_bounds__(NTHR, 2) void qmamba_main(
    const float* __restrict__ angles, const float* __restrict__ Wx,
    const float* __restrict__ Wdt, const float* __restrict__ bdt,
    const float* __restrict__ pc, const float* __restrict__ cp,
    float* __restrict__ out)
{
  __shared__ __align__(16) float tbl[SEQ][30];   // 61440 B (packed records)
  __shared__ float4 uuL[40];                     // 640 B
  __shared__ __align__(16) v2 ex0[1024];         // 8192 B
  __shared__ __align__(16) v2 ex1[1024];         // 8192 B
  __shared__ float  zb[8][16];                   // 512 B

  const int tid  = threadIdx.x;
  const int lane = tid & 63;
  const int wv   = tid >> 6;
  const int b    = blockIdx.x;

  // prologue 1: fused variational unitaries U = RZ(g)*RY(be)*RX(al)
  if (tid < 20) {
    int k = tid * 3;
    float al = 0.5f * cp[k], be = 0.5f * cp[k + 1], ga = 0.5f * cp[k + 2];
    float ca = __cosf(al), sa = __sinf(al);
    float cb = __cosf(be), sb = __sinf(be);
    float cg = __cosf(ga), sg = __sinf(ga);
    float2 M00 = make_float2(cb * ca,  sb * sa);
    float2 M01 = make_float2(-sb * ca, -cb * sa);
    float2 M10 = make_float2(sb * ca,  -cb * sa);
    float2 M11 = make_float2(cb * ca,  -sb * sa);
    float2 e0 = make_float2(cg, -sg), e1 = make_float2(cg, sg);
    auto cm = [](float2 a, float2 c) {
      return make_float2(a.x * c.x - a.y * c.y, a.x * c.y + a.y * c.x);
    };
    float2 u00 = cm(M00, e0), u01 = cm(M01, e0), u10 = cm(M10, e1), u11 = cm(M11, e1);
    uuL[2 * tid]     = make_float4(u00.x, u00.y, u01.x, u01.y);
    uuL[2 * tid + 1] = make_float4(u10.x, u10.y, u11.x, u11.y);
  }

  // prologue 2: per-step tables (one step per thread)
  {
    const int t = tid;
    const float* ar = angles + (size_t)(b * SEQ + t) * NQ;
    float a[NQ];
#pragma unroll
    for (int n = 0; n < NQ; ++n) a[n] = ar[n];
    float dtr[5];
#pragma unroll
    for (int r = 0; r < 5; ++r) {
      float acc = 0.f;
#pragma unroll
      for (int n = 0; n < NQ; ++n) acc += a[n] * Wx[r * NQ + n];
      dtr[r] = acc;
    }
    float* rec = &tbl[t][0];
#pragma unroll
    for (int w = 0; w < NQ; ++w) {
      float lin = bdt[w];
#pragma unroll
      for (int r = 0; r < 5; ++r) lin += dtr[r] * Wdt[w * 5 + r];
      float sp = lin > 0.f ? lin + log1pf(__expf(-lin)) : log1pf(__expf(lin));
      float th = tanhf(sp) * PIF;
      float fa = a[w] * th;
      rec[w]      = th;
      rec[10 + w] = __cosf(fa);
      rec[20 + w] = __sinf(fa);
    }
  }
  __syncthreads();

  float pch[4];
#pragma unroll
  for (int d = 0; d < 4; ++d) pch[d] = 0.5f * pc[d] * PIF;

  // wave-gate flat-sum coefficients (wires 5,1,3 <-> v bits 0,1,2)
  v2 cw0[8], cw1[8];
  {
    const int s5 = wv & 1, s1 = (wv >> 1) & 1, s3 = (wv >> 2) & 1;
    auto ent = [&](int g, int row, int col) -> v2 {
      float4 R = uuL[2 * g + row];
      return col ? v2{R.z, R.w} : v2{R.x, R.y};
    };
    auto cmul = [](v2 a, v2 c) -> v2 {
      return v2{a.x * c.x - a.y * c.y, a.x * c.y + a.y * c.x};
    };
#pragma unroll
    for (int v = 0; v < 8; ++v) {
      const int v5 = v & 1, v1 = (v >> 1) & 1, v3 = (v >> 2) & 1;
      cw0[v] = cmul(cmul(ent(5,  s5, s5 ^ v5), ent(1,  s1, s1 ^ v1)), ent(3,  s3, s3 ^ v3));
      cw1[v] = cmul(cmul(ent(15, s5, s5 ^ v5), ent(11, s1, s1 ^ v1)), ent(13, s3, s3 ^ v3));
    }
  }

  // Phase-B sign bits (register-cheap R9 form)
  unsigned PW0 = 0, PW1 = 0;
#pragma unroll
  for (int k = 0; k < 40; ++k) {
    const int m  = CT.mz[k / 10][k % 10];
    const int lm = lanePart(m), wm = wavePart8(m);
    unsigned flip = ((unsigned)((__popc(lane & lm) ^ __popc(wv & wm)) & 1)) ^ 1u;
    if (k < 32) PW0 |= flip << k; else PW1 |= flip << (k - 32);
  }

  // permutation write bases in storage space (R11-verified)
  int d4k = 0, dLk = 0;
  if (lane & 1)  { d4k ^= kmap(PC.c4[0]); dLk ^= kmap(PC.cL[0]); }
  if (lane & 2)  { d4k ^= kmap(PC.c4[5]); dLk ^= kmap(PC.cL[5]); }
  if (lane & 4)  { d4k ^= kmap(PC.c4[1]); dLk ^= kmap(PC.cL[1]); }
  if (lane & 8)  { d4k ^= kmap(PC.c4[7]); dLk ^= kmap(PC.cL[7]); }
  if (lane & 16) { d4k ^= kmap(PC.c4[3]); dLk ^= kmap(PC.cL[3]); }
  if (lane & 32) { d4k ^= kmap(PC.c4[9]); dLk ^= kmap(PC.cL[9]); }
  if (wv & 1)    { d4k ^= kmap(PC.c4[4]); dLk ^= kmap(PC.cL[4]); }
  if (wv & 2)    { d4k ^= kmap(PC.c4[8]); dLk ^= kmap(PC.cL[8]); }
  if (wv & 4)    { d4k ^= kmap(PC.c4[6]); dLk ^= kmap(PC.cL[6]); }
  const int sd4  = swzk(d4k);
  const int sdL  = swzk(dLk);
  const int sown = swzk((lane << 1) | (wv << 7));   // own r=0 storage slot (even)

  float hcw[NQ], hsw[NQ];
#pragma unroll
  for (int w = 0; w < NQ; ++w) { hcw[w] = 1.f; hsw[w] = 0.f; }

  v2 amp[2];

#pragma unroll 1
  for (int t = 0; t < SEQ; ++t) {
    float thv[10];
    {
      const float2* rq = (const float2*)&tbl[t][0];
#pragma unroll
      for (int j = 0; j < 5; ++j) { float2 q = rq[j]; thv[2 * j] = q.x; thv[2 * j + 1] = q.y; }
    }

    // ---- Phase A: real product state from RY(h)|0>
    float F;
    F  = (lane & 1)  ? hsw[9] : hcw[9];
    F *= (lane & 2)  ? hsw[4] : hcw[4];
    F *= (lane & 4)  ? hsw[8] : hcw[8];
    F *= (lane & 8)  ? hsw[2] : hcw[2];
    F *= (lane & 16) ? hsw[6] : hcw[6];
    F *= (lane & 32) ? hsw[0] : hcw[0];
    F *= (wv & 1)    ? hsw[5] : hcw[5];
    F *= (wv & 2)    ? hsw[1] : hcw[1];
    F *= (wv & 4)    ? hsw[3] : hcw[3];
    const float G0 = F * hcw[7];
    const float G1 = F * hsw[7];

    // ---- Phase B: fused 40-RZ phase
    float S0 = 0.f, S1 = 0.f;
#pragma unroll
    for (int k = 0; k < 40; ++k) {
      const int m  = CT.mz[k / 10][k % 10];
      float v = pch[k / 10] * thv[k % 10];
      unsigned fl = ((k < 32 ? (PW0 >> k) : (PW1 >> (k - 32))) & 1u) << 31;
      float sv = __int_as_float(__float_as_int(v) ^ fl);
      if ((m >> 2) & 1) S1 += sv; else S0 += sv;
    }
    {
      float sn, cs;
      __sincosf(S0 + S1, &sn, &cs); amp[0].x = G0 * cs; amp[0].y = G0 * sn;
      __sincosf(S0 - S1, &sn, &cs); amp[1].x = G1 * cs; amp[1].y = G1 * sn;
    }

    // ---- P4 permute merged with layer-0 wave gates ----
    ex0[sd4]        = amp[0];
    ex0[sd4 ^ SKC4] = amp[1];
    __syncthreads();
    {
      const float4* q4 = (const float4*)ex0;
      v2 a0 = {0.f, 0.f}, a1 = {0.f, 0.f};
#pragma unroll
      for (int v = 0; v < 8; ++v) {
        float4 q = q4[(sown ^ (v << 7)) >> 1];     // (r0.x r0.y r1.x r1.y)
        v2 c = cw0[v];
        a0.x += c.x * q.x - c.y * q.y;  a0.y += c.x * q.y + c.y * q.x;
        a1.x += c.x * q.z - c.y * q.w;  a1.y += c.x * q.w + c.y * q.z;
      }
      amp[0] = a0; amp[1] = a1;
    }
    // layer-0 local gates
    gate_lane2<32>(amp, uuL[0],  uuL[1],  lane);
    gate_lane2<8> (amp, uuL[4],  uuL[5],  lane);
    gate_lane2<2> (amp, uuL[8],  uuL[9],  lane);
    gate_lane2<16>(amp, uuL[12], uuL[13], lane);
    gate_reg1     (amp, uuL[14], uuL[15]);
    gate_lane2<4> (amp, uuL[16], uuL[17], lane);
    gate_lane2<1> (amp, uuL[18], uuL[19], lane);

    // ---- PL permute merged with layer-1 wave gates ----
    ex1[sdL]        = amp[0];
    ex1[sdL ^ SKCL] = amp[1];
    __syncthreads();
    {
      const float4* q4 = (const float4*)ex1;
      v2 a0 = {0.f, 0.f}, a1 = {0.f, 0.f};
#pragma unroll
      for (int v = 0; v < 8; ++v) {
        float4 q = q4[(sown ^ (v << 7)) >> 1];
        v2 c = cw1[v];
        a0.x += c.x * q.x - c.y * q.y;  a0.y += c.x * q.y + c.y * q.x;
        a1.x += c.x * q.z - c.y * q.w;  a1.y += c.x * q.w + c.y * q.z;
      }
      amp[0] = a0; amp[1] = a1;
    }
    // layer-1 local gates
    gate_lane2<32>(amp, uuL[20], uuL[21], lane);
    gate_lane2<8> (amp, uuL[24], uuL[25], lane);
    gate_lane2<2> (amp, uuL[28], uuL[29], lane);
    gate_lane2<16>(amp, uuL[32], uuL[33], lane);
    gate_reg1     (amp, uuL[34], uuL[35]);
    gate_lane2<4> (amp, uuL[36], uuL[37], lane);
    gate_lane2<1> (amp, uuL[38], uuL[39], lane);

    // ---- final PL permute merged with measurement ----
    ex0[sdL]        = amp[0];
    ex0[sdL ^ SKCL] = amp[1];
    __syncthreads();
    v2 pw5[2], pw1[2], pw3[2];
    {
      const float4* q4 = (const float4*)ex0;
      float4 qs = q4[sown >> 1];
      float4 q5 = q4[(sown ^ (1 << 7)) >> 1];
      float4 q1 = q4[(sown ^ (2 << 7)) >> 1];
      float4 q3 = q4[(sown ^ (4 << 7)) >> 1];
      amp[0] = v2{qs.x, qs.y}; amp[1] = v2{qs.z, qs.w};
      pw5[0] = v2{q5.x, q5.y}; pw5[1] = v2{q5.z, q5.w};
      pw1[0] = v2{q1.x, q1.y}; pw1[1] = v2{q1.z, q1.w};
      pw3[0] = v2{q3.x, q3.y}; pw3[1] = v2{q3.z, q3.w};
    }

    float cfv[10], sfv[10];
    {
      const float2* rq = (const float2*)&tbl[t][0];
#pragma unroll
      for (int j = 0; j < 5; ++j) {
        float2 qc = rq[5 + j], qsn = rq[10 + j];
        cfv[2 * j] = qc.x; cfv[2 * j + 1] = qc.y;
        sfv[2 * j] = qsn.x; sfv[2 * j + 1] = qsn.y;
      }
    }

    const float n0 = amp[0].x * amp[0].x + amp[0].y * amp[0].y;
    const float n1 = amp[1].x * amp[1].x + amp[1].y * amp[1].y;
    const float T0 = n0 + n1;
    const float T1 = n0 - n1;

    auto vdot2 = [](const v2* a, const v2* p) {
      v2 acc = a[0] * p[0] + a[1] * p[1];
      return acc.x + acc.y;
    };

    float zv[NQ];
    { float zp = (lane & 32) ? -T0 : T0; zv[0] = cfv[0] * zp - sfv[0] * xdot_lane2<32>(amp); }
    { float zp = (wv & 2)    ? -T0 : T0; zv[1] = cfv[1] * zp - sfv[1] * vdot2(amp, pw1); }
    { float zp = (lane & 8)  ? -T0 : T0; zv[2] = cfv[2] * zp - sfv[2] * xdot_lane2<8>(amp); }
    { float zp = (wv & 4)    ? -T0 : T0; zv[3] = cfv[3] * zp - sfv[3] * vdot2(amp, pw3); }
    { float zp = (lane & 2)  ? -T0 : T0; zv[4] = cfv[4] * zp - sfv[4] * xdot_lane2<2>(amp); }
    { float zp = (wv & 1)    ? -T0 : T0; zv[5] = cfv[5] * zp - sfv[5] * vdot2(amp, pw5); }
    { float zp = (lane & 16) ? -T0 : T0; zv[6] = cfv[6] * zp - sfv[6] * xdot_lane2<16>(amp); }
    { float xr = 2.f * (amp[0].x * amp[1].x + amp[0].y * amp[1].y);
      zv[7] = cfv[7] * T1 - sfv[7] * xr; }
    { float zp = (lane & 4)  ? -T0 : T0; zv[8] = cfv[8] * zp - sfv[8] * xdot_lane2<4>(amp); }
    { float zp = (lane & 1)  ? -T0 : T0; zv[9] = cfv[9] * zp - sfv[9] * xdot_lane2<1>(amp); }

    // per-wave lane reduction: 3 DPP stages + pack + 3 stages
#pragma unroll
    for (int w = 0; w < NQ; ++w) {
      zv[w] += lx<1>(zv[w]);
      zv[w] += lx<2>(zv[w]);
      zv[w] += lx<4>(zv[w]);
    }
    const int l7 = lane & 7;
    float c01 = (l7 & 1) ? zv[1] : zv[0];
    float c23 = (l7 & 1) ? zv[3] : zv[2];
    float c45 = (l7 & 1) ? zv[5] : zv[4];
    float c67 = (l7 & 1) ? zv[7] : zv[6];
    float c03 = (l7 & 2) ? c23 : c01;
    float c47 = (l7 & 2) ? c67 : c45;
    float pk  = (l7 & 4) ? c47 : c03;
    pk += lx<8>(pk);  pk += lx<16>(pk);  pk += lx<32>(pk);
    float z8 = zv[8]; z8 += lx<8>(z8); z8 += lx<16>(z8); z8 += lx<32>(z8);
    float z9 = zv[9]; z9 += lx<8>(z9); z9 += lx<16>(z9); z9 += lx<32>(z9);
    float zsel = pk;
    zsel = (lane == 8) ? z8 : zsel;
    zsel = (lane == 9) ? z9 : zsel;

    // cross-wave combine + raw z store + h for next step
    if (lane < NQ) zb[wv][lane] = zsel;
    __syncthreads();
    float z = 0.f;
    if (lane < NQ) {
      z = zb[0][lane] + zb[1][lane] + zb[2][lane] + zb[3][lane]
        + zb[4][lane] + zb[5][lane] + zb[6][lane] + zb[7][lane];
      if (wv == 0) out[(size_t)(b * SEQ + t) * NQ + lane] = z;
    }
    float sn_h, cs_h;
    __sincosf(0.5f * z, &sn_h, &cs_h);
#pragma unroll
    for (int w = 0; w < NQ; ++w) { hcw[w] = rdl(cs_h, w); hsw[w] = rdl(sn_h, w); }
  }
}

// ---------------- post kernel: out = C*z + D*a, in place ----------------
__global__ __launch_bounds__(256) void qmamba_post(
    const float* __restrict__ angles, const float* __restrict__ Wx,
    const float* __restrict__ Dg, float* __restrict__ out)
{
  int i = blockIdx.x * 256 + threadIdx.x;
  if (i >= NB * SEQ * NQ) return;
  int w  = i % NQ;
  int bt = i / NQ;
  const float* a = angles + (size_t)bt * NQ;
  float C = 0.f;
#pragma unroll
  for (int n = 0; n < NQ; ++n) C += a[n] * Wx[(15 + w) * NQ + n];
  float z = out[i];
  out[i] = C * z + Dg[w] * a[w];
}

extern "C" void kernel_launch(void* const* d_in, const int* in_sizes, int n_in,
                              void* d_out, int out_size, void* d_ws, size_t ws_size,
                              hipStream_t stream) {
  (void)in_sizes; (void)n_in; (void)out_size; (void)d_ws; (void)ws_size;
  const float* angles = (const float*)d_in[0];
  const float* Wx     = (const float*)d_in[1];
  const float* Wdt    = (const float*)d_in[2];
  const float* bdt    = (const float*)d_in[3];
  const float* pc     = (const float*)d_in[4];
  const float* cp     = (const float*)d_in[5];
  const float* Dg     = (const float*)d_in[6];
  float* out = (float*)d_out;
  hipLaunchKernelGGL(qmamba_main, dim3(NB), dim3(NTHR), 0, stream,
                     angles, Wx, Wdt, bdt, pc, cp, out);
  hipLaunchKernelGGL(qmamba_post, dim3((NB * SEQ * NQ + 255) / 256), dim3(256), 0, stream,
                     angles, Wx, Dg, out);
}